// Round 4
// baseline (932.681 us; speedup 1.0000x reference)
//
#include <hip/hip_runtime.h>
#include <math.h>

// ---------------------------------------------------------------------------
// DevignLite: 3-layer GCN + mean/max pool + MLP head.  All fp32.
// N=100000 nodes, E=1600000 edges, D=64, G=256 graphs.
// Round 3:
//  - Feature-chunked xws layout: 8 slabs of [N][8] floats (3.2 MB = fits one
//    XCD L2).  k_aggregate uses blockIdx%8 = slab -> XCD affinity, so each
//    XCD's gathers stay L2-resident (round-2 profile: 271 MB FETCH vs 25.6 MB
//    working set = L2 capacity misses).
//  - LDS-free matmul: lane = row, W via wave-uniform (scalar) loads, 64
//    accumulators/lane.  Kills the 320-ds_read-per-wave LDS-pipe bottleneck.
// ---------------------------------------------------------------------------

#define BKT_LOG 9
#define BKT (1 << BKT_LOG)   // 512 nodes per coarse bucket
#define CHUNK 2048           // edges per k_part block (8 per thread)

__global__ void k_zero(float* p, long n) {
  long i = (long)blockIdx.x * blockDim.x + threadIdx.x;
  if (i < n) p[i] = 0.0f;
}

// coarse histogram of dst >> BKT_LOG
__global__ __launch_bounds__(256) void k_chist(const int* __restrict__ dst,
                                               int* __restrict__ chist, int E, int B) {
  __shared__ int h[256];
  h[threadIdx.x] = 0;
  __syncthreads();
  for (long e = (long)blockIdx.x * blockDim.x + threadIdx.x; e < E;
       e += (long)gridDim.x * blockDim.x)
    atomicAdd(&h[dst[e] >> BKT_LOG], 1);
  __syncthreads();
  if (threadIdx.x < B && h[threadIdx.x]) atomicAdd(&chist[threadIdx.x], h[threadIdx.x]);
}

// exclusive scan of chist[B] -> cbase[B+1]; cursor copy -> gcur
__global__ __launch_bounds__(256) void k_cscan(const int* __restrict__ chist,
                                               int* __restrict__ cbase,
                                               int* __restrict__ gcur, int E, int B) {
  __shared__ int s[256];
  int v = (threadIdx.x < B) ? chist[threadIdx.x] : 0;
  s[threadIdx.x] = v;
  __syncthreads();
  for (int d = 1; d < 256; d <<= 1) {
    int t = (threadIdx.x >= (unsigned)d) ? s[threadIdx.x - d] : 0;
    __syncthreads();
    s[threadIdx.x] += t;
    __syncthreads();
  }
  if (threadIdx.x < B) {
    int ex = s[threadIdx.x] - v;
    cbase[threadIdx.x] = ex;
    gcur[threadIdx.x] = ex;
  }
  if (threadIdx.x == B) cbase[B] = E;
}

// partition pass: scatter (src,dst) pairs into coarse-bucket order.
__global__ __launch_bounds__(256) void k_part(const int* __restrict__ src,
                                              const int* __restrict__ dst,
                                              int* __restrict__ gcur,
                                              int2* __restrict__ ebuf, int E, int B) {
  __shared__ int h[256], base[256], cur[256];
  long c0 = (long)blockIdx.x * CHUNK;
  int m = (int)min((long)CHUNK, (long)E - c0);
  int sreg[8], dreg[8];
  h[threadIdx.x] = 0;
  __syncthreads();
#pragma unroll
  for (int j = 0; j < 8; j++) {
    int idx = threadIdx.x + j * 256;
    if (idx < m) {
      sreg[j] = src[c0 + idx];
      dreg[j] = dst[c0 + idx];
      atomicAdd(&h[dreg[j] >> BKT_LOG], 1);
    }
  }
  __syncthreads();
  if (threadIdx.x < B && h[threadIdx.x])
    base[threadIdx.x] = atomicAdd(&gcur[threadIdx.x], h[threadIdx.x]);
  cur[threadIdx.x] = 0;
  __syncthreads();
#pragma unroll
  for (int j = 0; j < 8; j++) {
    int idx = threadIdx.x + j * 256;
    if (idx < m) {
      int k = dreg[j] >> BKT_LOG;
      int p = base[k] + atomicAdd(&cur[k], 1);
      ebuf[p] = make_int2(sreg[j], dreg[j]);
    }
  }
}

// per-bucket: node histogram + scan in LDS -> off/dinv, then place csrc.
__global__ __launch_bounds__(512) void k_bplace(const int2* __restrict__ ebuf,
                                                const int* __restrict__ cbase,
                                                int* __restrict__ off,
                                                int* __restrict__ csrc,
                                                float* __restrict__ dinv,
                                                int N, int E) {
  __shared__ int s[512];
  __shared__ int cur[512];
  int b = blockIdx.x, tid = threadIdx.x;
  int n0 = b << BKT_LOG;
  int nn = min(BKT, N - n0);
  int e0 = cbase[b], e1 = cbase[b + 1];
  s[tid] = 0;
  __syncthreads();
  for (int e = e0 + tid; e < e1; e += 512) atomicAdd(&s[ebuf[e].y - n0], 1);
  __syncthreads();
  int deg = s[tid];
  for (int d = 1; d < 512; d <<= 1) {
    int t = (tid >= d) ? s[tid - d] : 0;
    __syncthreads();
    s[tid] += t;
    __syncthreads();
  }
  int excl = s[tid] - deg;
  if (tid < nn) {
    off[n0 + tid] = e0 + excl;
    dinv[n0 + tid] = 1.0f / sqrtf((float)(1 + deg));
  }
  cur[tid] = excl;
  __syncthreads();
  for (int e = e0 + tid; e < e1; e += 512) {
    int2 p = ebuf[e];
    int pos = e0 + atomicAdd(&cur[p.y - n0], 1);
    csrc[pos] = p.x;
  }
  if (b == 0 && tid == 0) off[N] = E;
}

// ---------------------------------------------------------------------------
// Matmul, lane = row.  Input either raw chunked slabs (8 x [n][8]) or
// embedding rows; W read with wave-uniform loads (scalarizable); 64 fp32
// accumulators per lane.  Output written in chunked layout, scaled by dinv.
// ---------------------------------------------------------------------------
template <bool EMB, bool ACT>
__global__ __launch_bounds__(256) void k_matmul(const float* __restrict__ xin,
                                                const int* __restrict__ tok,
                                                const float* __restrict__ emb,
                                                const float* __restrict__ W,
                                                const float* __restrict__ bprev,
                                                const float* __restrict__ dinv,
                                                float* __restrict__ xw, int n) {
  long row = (long)blockIdx.x * 256 + threadIdx.x;
  if (row >= n) return;
  const float4* W4 = (const float4*)W;
  const float4* b4 = (const float4*)bprev;
  const float4* er = nullptr;
  if (EMB) er = (const float4*)(emb + (size_t)tok[row] * 64);
  size_t xoff = (size_t)row * 8;
  float acc[64];
#pragma unroll
  for (int i = 0; i < 64; i++) acc[i] = 0.f;

  for (int d4 = 0; d4 < 16; d4++) {
    float4 xv;
    if (EMB) {
      xv = er[d4];
    } else {
      int c = d4 >> 1, h = d4 & 1;
      xv = *(const float4*)(xin + (size_t)c * n * 8 + xoff + h * 4);
    }
    if (ACT) {
      float4 bb = b4[d4];
      xv.x = fmaxf(xv.x + bb.x, 0.f);
      xv.y = fmaxf(xv.y + bb.y, 0.f);
      xv.z = fmaxf(xv.z + bb.z, 0.f);
      xv.w = fmaxf(xv.w + bb.w, 0.f);
    }
    const float xs[4] = {xv.x, xv.y, xv.z, xv.w};
#pragma unroll
    for (int r = 0; r < 4; r++) {
      const float4* wr = W4 + (size_t)(d4 * 4 + r) * 16;   // uniform address
      float x = xs[r];
#pragma unroll
      for (int cb = 0; cb < 16; cb++) {
        float4 w = wr[cb];
        acc[cb * 4 + 0] += x * w.x;
        acc[cb * 4 + 1] += x * w.y;
        acc[cb * 4 + 2] += x * w.z;
        acc[cb * 4 + 3] += x * w.w;
      }
    }
  }
  float di = dinv[row];
#pragma unroll
  for (int c = 0; c < 8; c++) {
    float4 o0 = make_float4(acc[c * 8 + 0] * di, acc[c * 8 + 1] * di,
                            acc[c * 8 + 2] * di, acc[c * 8 + 3] * di);
    float4 o1 = make_float4(acc[c * 8 + 4] * di, acc[c * 8 + 5] * di,
                            acc[c * 8 + 6] * di, acc[c * 8 + 7] * di);
    float* p = xw + (size_t)c * n * 8 + xoff;
    *(float4*)p = o0;
    *(float4*)(p + 4) = o1;
  }
}

// ---------------------------------------------------------------------------
// Aggregate, chunk-parallel with XCD affinity.  blockIdx%8 = slab c; one wave
// per dst node: 64 lanes = 8 edges x 8 feats; xor-shuffle reduce over octets.
// agg_c[t] = dinv[t] * (xws_c[t] + sum_{s in in(t)} xws_c[s])
// ---------------------------------------------------------------------------
__global__ __launch_bounds__(256) void k_aggregate(const int* __restrict__ off,
                                                   const int* __restrict__ csrc,
                                                   const float* __restrict__ dinv,
                                                   const float* __restrict__ xws,
                                                   float* __restrict__ agg, int n) {
  int c = blockIdx.x & 7;
  int t = (blockIdx.x >> 3) * 4 + (threadIdx.x >> 6);
  if (t >= n) return;
  int lane = threadIdx.x & 63;
  int f = lane & 7, eSub = lane >> 3;
  const float* xc = xws + (size_t)c * n * 8;
  float acc = (eSub == 0) ? xc[(size_t)t * 8 + f] : 0.f;   // self-loop term
  int e0 = off[t], e1 = off[t + 1];
  for (int base = e0; base < e1; base += 8) {
    int idx = base + eSub;
    if (idx < e1) {
      int s = csrc[idx];
      acc += xc[(size_t)s * 8 + f];
    }
  }
  acc += __shfl_xor(acc, 8);
  acc += __shfl_xor(acc, 16);
  acc += __shfl_xor(acc, 32);
  if (eSub == 0) agg[(size_t)c * n * 8 + (size_t)t * 8 + f] = acc * dinv[t];
}

// batch is sorted: per-wave register segment reduction, flush on boundary.
// x is in chunked layout: per-lane base offset handles the slab mapping.
__global__ __launch_bounds__(256) void k_pool(const float* __restrict__ x,
                                              const float* __restrict__ b,
                                              const int* __restrict__ batch,
                                              float* __restrict__ hsum,
                                              float* __restrict__ hmax,
                                              int* __restrict__ cntg, int n) {
  int wid = (blockIdx.x * blockDim.x + threadIdx.x) >> 6;
  int lane = threadIdx.x & 63;
  int i0 = wid * 64;
  if (i0 >= n) return;
  int i1 = min(i0 + 64, n);
  float bb = b[lane];
  size_t boff = (size_t)(lane >> 3) * n * 8 + (lane & 7);
  int batch_l = (i0 + lane < n) ? batch[i0 + lane] : 0;
  float gsum = 0.f, gmax = 0.f;
  int cur = __shfl(batch_l, 0);
  int c = 0;
  for (int i = i0; i < i1; i++) {
    int g = __shfl(batch_l, i - i0);
    if (g != cur) {
      atomicAdd(&hsum[cur * 64 + lane], gsum);
      atomicMax((int*)&hmax[cur * 64 + lane], __float_as_int(gmax));
      if (lane == 0) atomicAdd(&cntg[cur], c);
      gsum = 0.f; gmax = 0.f; c = 0; cur = g;
    }
    float v = fmaxf(x[boff + (size_t)i * 8] + bb, 0.0f);
    gsum += v;
    gmax = fmaxf(gmax, v);
    c++;
  }
  atomicAdd(&hsum[cur * 64 + lane], gsum);
  atomicMax((int*)&hmax[cur * 64 + lane], __float_as_int(gmax));
  if (lane == 0) atomicAdd(&cntg[cur], c);
}

// one block (64 threads) per graph: logits = relu(h@Wc1+bc1)@Wc2+bc2
__global__ __launch_bounds__(64) void k_cls(const float* __restrict__ hsum,
                                            const float* __restrict__ hmax,
                                            const int* __restrict__ cnt,
                                            const float* __restrict__ Wc1,
                                            const float* __restrict__ bc1,
                                            const float* __restrict__ Wc2,
                                            const float* __restrict__ bc2,
                                            float* __restrict__ out) {
  __shared__ float h[128];
  __shared__ float hid[64];
  int g = blockIdx.x, j = threadIdx.x;
  int c = cnt[g];
  float cf = (float)(c > 0 ? c : 1);
  h[j] = hsum[g * 64 + j] / cf;
  h[64 + j] = hmax[g * 64 + j];
  __syncthreads();
  float acc = bc1[j];
  for (int k = 0; k < 128; k++) acc += h[k] * Wc1[k * 64 + j];
  hid[j] = fmaxf(acc, 0.f);
  __syncthreads();
  if (j < 2) {
    float a = bc2[j];
    for (int k = 0; k < 64; k++) a += hid[k] * Wc2[k * 2 + j];
    out[g * 2 + j] = a;
  }
}

extern "C" void kernel_launch(void* const* d_in, const int* in_sizes, int n_in,
                              void* d_out, int out_size, void* d_ws, size_t ws_size,
                              hipStream_t stream) {
  const int N = in_sizes[0];
  const int E = in_sizes[1] / 2;
  const int G = out_size / 2;
  const int B = (N + BKT - 1) >> BKT_LOG;   // coarse buckets (196 for N=100000)

  const int* tok   = (const int*)d_in[0];
  const int* ei    = (const int*)d_in[1];
  const int* batch = (const int*)d_in[2];
  const float* emb = (const float*)d_in[3];
  const float* W0 = (const float*)d_in[4];  const float* b0 = (const float*)d_in[5];
  const float* W1 = (const float*)d_in[6];  const float* b1 = (const float*)d_in[7];
  const float* W2 = (const float*)d_in[8];  const float* b2 = (const float*)d_in[9];
  const float* Wc1 = (const float*)d_in[10]; const float* bc1 = (const float*)d_in[11];
  const float* Wc2 = (const float*)d_in[12]; const float* bc2 = (const float*)d_in[13];
  const int* srcp = ei;
  const int* dstp = ei + E;

  // ---- workspace carve-up (4-byte units) ----
  int* off    = (int*)d_ws;                      // N+2 (pad)
  int* csrc   = off + N + 2;                     // E
  float* dinv = (float*)(csrc + E);              // N
  int* chist  = (int*)(dinv + N);                // 256
  int* cbase  = chist + 256;                     // 256 (B+1 used)
  int* gcur   = cbase + 256;                     // 256
  float* bufA = (float*)(gcur + 256);            // N*64
  float* bufB = bufA + (size_t)N * 64;           // N*64
  float* bufC = bufB + (size_t)N * 64;           // N*64
  int2* ebuf  = (int2*)bufC;                     // E pairs (dead before bufC use)
  float* hsum = bufC + (size_t)N * 64;           // G*64
  float* hmax = hsum + (size_t)G * 64;           // G*64
  int*   cntg = (int*)(hmax + (size_t)G * 64);   // G

  auto cdiv = [](long a, long b) { return (int)((a + b - 1) / b); };
  const int aggBlocks = 8 * cdiv(N, 4);          // blockIdx%8 = slab -> XCD

  // ---- CSR build (single-writer placement) ----
  k_zero<<<1, 256, 0, stream>>>((float*)chist, 256);
  k_chist<<<cdiv(E, CHUNK), 256, 0, stream>>>(dstp, chist, E, B);
  k_cscan<<<1, 256, 0, stream>>>(chist, cbase, gcur, E, B);
  k_part<<<cdiv(E, CHUNK), 256, 0, stream>>>(srcp, dstp, gcur, ebuf, E, B);
  k_bplace<<<B, 512, 0, stream>>>(ebuf, cbase, off, csrc, dinv, N, E);

  // ---- 3 GCN layers ----
  k_matmul<true, false><<<cdiv(N, 256), 256, 0, stream>>>(nullptr, tok, emb, W0, nullptr, dinv, bufA, N);
  k_aggregate<<<aggBlocks, 256, 0, stream>>>(off, csrc, dinv, bufA, bufB, N);

  k_matmul<false, true><<<cdiv(N, 256), 256, 0, stream>>>(bufB, nullptr, nullptr, W1, b0, dinv, bufC, N);
  k_aggregate<<<aggBlocks, 256, 0, stream>>>(off, csrc, dinv, bufC, bufA, N);

  k_matmul<false, true><<<cdiv(N, 256), 256, 0, stream>>>(bufA, nullptr, nullptr, W2, b1, dinv, bufB, N);
  k_aggregate<<<aggBlocks, 256, 0, stream>>>(off, csrc, dinv, bufB, bufC, N);

  // ---- pooling (relu+b2 fused) ----
  k_zero<<<cdiv((long)G * 129, 256), 256, 0, stream>>>(hsum, (long)G * 129);
  k_pool<<<cdiv(N, 256), 256, 0, stream>>>(bufC, b2, batch, hsum, hmax, cntg, N);

  // ---- classifier head ----
  k_cls<<<G, 64, 0, stream>>>(hsum, hmax, cntg, Wc1, bc1, Wc2, bc2, (float*)d_out);
}

// Round 5
// 515.790 us; speedup vs baseline: 1.8083x; 1.8083x over previous
//
#include <hip/hip_runtime.h>
#include <hip/hip_fp16.h>
#include <math.h>

// ---------------------------------------------------------------------------
// DevignLite: 3-layer GCN + mean/max pool + MLP head.  N=100000, E=1.6M,
// D=64, G=256.
// Round 5: round-3 aggregate structure (coalesced row gathers, one pass over
// the edge list) + fp16 xws rows (128 B) to halve gather bytes and working
// set (12.8 MB).  xws scaled by 256*dinv[src] (matmul epilogue), aggregate
// scales by dinv[dst]/256 -> keeps fp16 values in normal range.  All
// accumulation fp32.  Round-4 lesson: 8-slab chunking made the gather
// scattered + 8x per-wave overhead -> issue-bound regression; reverted.
// ---------------------------------------------------------------------------

#define BKT_LOG 9
#define BKT (1 << BKT_LOG)   // 512 nodes per coarse bucket
#define CHUNK 2048           // edges per k_part block (8 per thread)

__global__ void k_zero(float* p, long n) {
  long i = (long)blockIdx.x * blockDim.x + threadIdx.x;
  if (i < n) p[i] = 0.0f;
}

// coarse histogram of dst >> BKT_LOG
__global__ __launch_bounds__(256) void k_chist(const int* __restrict__ dst,
                                               int* __restrict__ chist, int E, int B) {
  __shared__ int h[256];
  h[threadIdx.x] = 0;
  __syncthreads();
  for (long e = (long)blockIdx.x * blockDim.x + threadIdx.x; e < E;
       e += (long)gridDim.x * blockDim.x)
    atomicAdd(&h[dst[e] >> BKT_LOG], 1);
  __syncthreads();
  if (threadIdx.x < B && h[threadIdx.x]) atomicAdd(&chist[threadIdx.x], h[threadIdx.x]);
}

// exclusive scan of chist[B] -> cbase[B+1]; cursor copy -> gcur
__global__ __launch_bounds__(256) void k_cscan(const int* __restrict__ chist,
                                               int* __restrict__ cbase,
                                               int* __restrict__ gcur, int E, int B) {
  __shared__ int s[256];
  int v = (threadIdx.x < B) ? chist[threadIdx.x] : 0;
  s[threadIdx.x] = v;
  __syncthreads();
  for (int d = 1; d < 256; d <<= 1) {
    int t = (threadIdx.x >= (unsigned)d) ? s[threadIdx.x - d] : 0;
    __syncthreads();
    s[threadIdx.x] += t;
    __syncthreads();
  }
  if (threadIdx.x < B) {
    int ex = s[threadIdx.x] - v;
    cbase[threadIdx.x] = ex;
    gcur[threadIdx.x] = ex;
  }
  if (threadIdx.x == B) cbase[B] = E;
}

// partition pass: scatter (src,dst) pairs into coarse-bucket order.
// Block-exclusive contiguous slices -> single writer per cache line.
__global__ __launch_bounds__(256) void k_part(const int* __restrict__ src,
                                              const int* __restrict__ dst,
                                              int* __restrict__ gcur,
                                              int2* __restrict__ ebuf, int E, int B) {
  __shared__ int h[256], base[256], cur[256];
  long c0 = (long)blockIdx.x * CHUNK;
  int m = (int)min((long)CHUNK, (long)E - c0);
  int sreg[8], dreg[8];
  h[threadIdx.x] = 0;
  __syncthreads();
#pragma unroll
  for (int j = 0; j < 8; j++) {
    int idx = threadIdx.x + j * 256;
    if (idx < m) {
      sreg[j] = src[c0 + idx];
      dreg[j] = dst[c0 + idx];
      atomicAdd(&h[dreg[j] >> BKT_LOG], 1);
    }
  }
  __syncthreads();
  if (threadIdx.x < B && h[threadIdx.x])
    base[threadIdx.x] = atomicAdd(&gcur[threadIdx.x], h[threadIdx.x]);
  cur[threadIdx.x] = 0;
  __syncthreads();
#pragma unroll
  for (int j = 0; j < 8; j++) {
    int idx = threadIdx.x + j * 256;
    if (idx < m) {
      int k = dreg[j] >> BKT_LOG;
      int p = base[k] + atomicAdd(&cur[k], 1);
      ebuf[p] = make_int2(sreg[j], dreg[j]);
    }
  }
}

// per-bucket: node histogram + scan in LDS -> off/dinv, then place csrc.
__global__ __launch_bounds__(512) void k_bplace(const int2* __restrict__ ebuf,
                                                const int* __restrict__ cbase,
                                                int* __restrict__ off,
                                                int* __restrict__ csrc,
                                                float* __restrict__ dinv,
                                                int N, int E) {
  __shared__ int s[512];
  __shared__ int cur[512];
  int b = blockIdx.x, tid = threadIdx.x;
  int n0 = b << BKT_LOG;
  int nn = min(BKT, N - n0);
  int e0 = cbase[b], e1 = cbase[b + 1];
  s[tid] = 0;
  __syncthreads();
  for (int e = e0 + tid; e < e1; e += 512) atomicAdd(&s[ebuf[e].y - n0], 1);
  __syncthreads();
  int deg = s[tid];
  for (int d = 1; d < 512; d <<= 1) {
    int t = (tid >= d) ? s[tid - d] : 0;
    __syncthreads();
    s[tid] += t;
    __syncthreads();
  }
  int excl = s[tid] - deg;
  if (tid < nn) {
    off[n0 + tid] = e0 + excl;
    dinv[n0 + tid] = 1.0f / sqrtf((float)(1 + deg));
  }
  cur[tid] = excl;
  __syncthreads();
  for (int e = e0 + tid; e < e1; e += 512) {
    int2 p = ebuf[e];
    int pos = e0 + atomicAdd(&cur[p.y - n0], 1);
    csrc[pos] = p.x;
  }
  if (b == 0 && tid == 0) off[N] = E;
}

// ---------------------------------------------------------------------------
// Matmul, lane = row.  xw_h[row] = act(xin[row]) @ W * (256*dinv[row]), fp16.
// W read with wave-uniform loads; 64 fp32 accumulators per lane.
// ---------------------------------------------------------------------------
template <bool EMB, bool ACT>
__global__ __launch_bounds__(256) void k_matmul(const float* __restrict__ xin,
                                                const int* __restrict__ tok,
                                                const float* __restrict__ emb,
                                                const float* __restrict__ W,
                                                const float* __restrict__ bprev,
                                                const float* __restrict__ dinv,
                                                __half2* __restrict__ xwh, int n) {
  long row = (long)blockIdx.x * 256 + threadIdx.x;
  if (row >= n) return;
  const float4* W4 = (const float4*)W;
  const float4* b4 = (const float4*)bprev;
  const float4* xr;
  if (EMB) xr = (const float4*)(emb + (size_t)tok[row] * 64);
  else     xr = (const float4*)(xin + (size_t)row * 64);
  float acc[64];
#pragma unroll
  for (int i = 0; i < 64; i++) acc[i] = 0.f;

  for (int d4 = 0; d4 < 16; d4++) {
    float4 xv = xr[d4];
    if (ACT) {
      float4 bb = b4[d4];
      xv.x = fmaxf(xv.x + bb.x, 0.f);
      xv.y = fmaxf(xv.y + bb.y, 0.f);
      xv.z = fmaxf(xv.z + bb.z, 0.f);
      xv.w = fmaxf(xv.w + bb.w, 0.f);
    }
    const float xs[4] = {xv.x, xv.y, xv.z, xv.w};
#pragma unroll
    for (int r = 0; r < 4; r++) {
      const float4* wr = W4 + (size_t)(d4 * 4 + r) * 16;   // uniform address
      float x = xs[r];
#pragma unroll
      for (int cb = 0; cb < 16; cb++) {
        float4 w = wr[cb];
        acc[cb * 4 + 0] += x * w.x;
        acc[cb * 4 + 1] += x * w.y;
        acc[cb * 4 + 2] += x * w.z;
        acc[cb * 4 + 3] += x * w.w;
      }
    }
  }
  float di = dinv[row] * 256.0f;       // fp16-range scale, undone in aggregate
  __half2 hh[32];
#pragma unroll
  for (int c = 0; c < 32; c++)
    hh[c] = __float22half2_rn(make_float2(acc[2 * c] * di, acc[2 * c + 1] * di));
  uint4* dst = (uint4*)(xwh + (size_t)row * 32);
  const uint4* src = (const uint4*)hh;
#pragma unroll
  for (int k = 0; k < 8; k++) dst[k] = src[k];
}

// ---------------------------------------------------------------------------
// Aggregate: one wave per dst node.  Lanes 0-31 = even edge, 32-63 = odd edge
// of each pair; each lane covers feats (2*f2, 2*f2+1) of a 128 B fp16 row.
// agg[t] = (dinv[t]/256) * (xh[t] + sum_{s in in(t)} xh[s])   (fp32 out)
// ---------------------------------------------------------------------------
__global__ __launch_bounds__(256) void k_aggregate(const int* __restrict__ off,
                                                   const int* __restrict__ csrc,
                                                   const float* __restrict__ dinv,
                                                   const __half2* __restrict__ xh,
                                                   float* __restrict__ agg, int n) {
  int gt = blockIdx.x * blockDim.x + threadIdx.x;
  int t = gt >> 6, lane = gt & 63;
  if (t >= n) return;
  int half = lane >> 5, f2 = lane & 31;
  float2 acc = make_float2(0.f, 0.f);
  if (half == 0) acc = __half22float2(xh[(size_t)t * 32 + f2]);   // self term
  int e0 = off[t], e1 = off[t + 1];
  for (int base = e0; base < e1; base += 64) {
    int m = min(64, e1 - base);
    int s_l = (lane < m) ? csrc[base + lane] : -1;
#pragma unroll 8
    for (int j = 0; j < m; j += 2) {
      int s = __shfl(s_l, j + half);
      if (s >= 0) {
        float2 v = __half22float2(xh[(size_t)s * 32 + f2]);
        acc.x += v.x;
        acc.y += v.y;
      }
    }
  }
  acc.x += __shfl_xor(acc.x, 32);
  acc.y += __shfl_xor(acc.y, 32);
  if (half == 0) {
    float sc = dinv[t] * (1.0f / 256.0f);
    *(float2*)(agg + (size_t)t * 64 + 2 * f2) = make_float2(acc.x * sc, acc.y * sc);
  }
}

// batch is sorted: per-wave register segment reduction, flush on boundary.
__global__ __launch_bounds__(256) void k_pool(const float* __restrict__ x,
                                              const float* __restrict__ b,
                                              const int* __restrict__ batch,
                                              float* __restrict__ hsum,
                                              float* __restrict__ hmax,
                                              int* __restrict__ cntg, int n) {
  int wid = (blockIdx.x * blockDim.x + threadIdx.x) >> 6;
  int lane = threadIdx.x & 63;
  int i0 = wid * 64;
  if (i0 >= n) return;
  int i1 = min(i0 + 64, n);
  float bb = b[lane];
  int batch_l = (i0 + lane < n) ? batch[i0 + lane] : 0;
  float gsum = 0.f, gmax = 0.f;
  int cur = __shfl(batch_l, 0);
  int c = 0;
  for (int i = i0; i < i1; i++) {
    int g = __shfl(batch_l, i - i0);
    if (g != cur) {
      atomicAdd(&hsum[cur * 64 + lane], gsum);
      atomicMax((int*)&hmax[cur * 64 + lane], __float_as_int(gmax));
      if (lane == 0) atomicAdd(&cntg[cur], c);
      gsum = 0.f; gmax = 0.f; c = 0; cur = g;
    }
    float v = fmaxf(x[(long)i * 64 + lane] + bb, 0.0f);
    gsum += v;
    gmax = fmaxf(gmax, v);
    c++;
  }
  atomicAdd(&hsum[cur * 64 + lane], gsum);
  atomicMax((int*)&hmax[cur * 64 + lane], __float_as_int(gmax));
  if (lane == 0) atomicAdd(&cntg[cur], c);
}

// one block (64 threads) per graph: logits = relu(h@Wc1+bc1)@Wc2+bc2
__global__ __launch_bounds__(64) void k_cls(const float* __restrict__ hsum,
                                            const float* __restrict__ hmax,
                                            const int* __restrict__ cnt,
                                            const float* __restrict__ Wc1,
                                            const float* __restrict__ bc1,
                                            const float* __restrict__ Wc2,
                                            const float* __restrict__ bc2,
                                            float* __restrict__ out) {
  __shared__ float h[128];
  __shared__ float hid[64];
  int g = blockIdx.x, j = threadIdx.x;
  int c = cnt[g];
  float cf = (float)(c > 0 ? c : 1);
  h[j] = hsum[g * 64 + j] / cf;
  h[64 + j] = hmax[g * 64 + j];
  __syncthreads();
  float acc = bc1[j];
  for (int k = 0; k < 128; k++) acc += h[k] * Wc1[k * 64 + j];
  hid[j] = fmaxf(acc, 0.f);
  __syncthreads();
  if (j < 2) {
    float a = bc2[j];
    for (int k = 0; k < 64; k++) a += hid[k] * Wc2[k * 2 + j];
    out[g * 2 + j] = a;
  }
}

extern "C" void kernel_launch(void* const* d_in, const int* in_sizes, int n_in,
                              void* d_out, int out_size, void* d_ws, size_t ws_size,
                              hipStream_t stream) {
  const int N = in_sizes[0];
  const int E = in_sizes[1] / 2;
  const int G = out_size / 2;
  const int B = (N + BKT - 1) >> BKT_LOG;

  const int* tok   = (const int*)d_in[0];
  const int* ei    = (const int*)d_in[1];
  const int* batch = (const int*)d_in[2];
  const float* emb = (const float*)d_in[3];
  const float* W0 = (const float*)d_in[4];  const float* b0 = (const float*)d_in[5];
  const float* W1 = (const float*)d_in[6];  const float* b1 = (const float*)d_in[7];
  const float* W2 = (const float*)d_in[8];  const float* b2 = (const float*)d_in[9];
  const float* Wc1 = (const float*)d_in[10]; const float* bc1 = (const float*)d_in[11];
  const float* Wc2 = (const float*)d_in[12]; const float* bc2 = (const float*)d_in[13];
  const int* srcp = ei;
  const int* dstp = ei + E;

  // ---- workspace carve-up (4-byte units) ----
  int* off    = (int*)d_ws;                      // N+2
  int* csrc   = off + N + 2;                     // E
  float* dinv = (float*)(csrc + E);              // N
  int* chist  = (int*)(dinv + N);                // 256
  int* cbase  = chist + 256;                     // 256 (B+1 used)
  int* gcur   = cbase + 256;                     // 256
  __half2* xh = (__half2*)(gcur + 256);          // N*32 half2 (12.8 MB)
  float* bufA = (float*)((int*)(gcur + 256) + (size_t)N * 32);  // N*64 fp32
  float* bufB = bufA + (size_t)N * 64;           // N*64 fp32
  int2* ebuf  = (int2*)bufA;                     // E pairs (dead before agg0)
  float* hsum = bufB + (size_t)N * 64;           // G*64
  float* hmax = hsum + (size_t)G * 64;           // G*64
  int*   cntg = (int*)(hmax + (size_t)G * 64);   // G

  auto cdiv = [](long a, long b) { return (int)((a + b - 1) / b); };

  // ---- CSR build (single-writer placement) ----
  k_zero<<<1, 256, 0, stream>>>((float*)chist, 256);
  k_chist<<<cdiv(E, CHUNK), 256, 0, stream>>>(dstp, chist, E, B);
  k_cscan<<<1, 256, 0, stream>>>(chist, cbase, gcur, E, B);
  k_part<<<cdiv(E, CHUNK), 256, 0, stream>>>(srcp, dstp, gcur, ebuf, E, B);
  k_bplace<<<B, 512, 0, stream>>>(ebuf, cbase, off, csrc, dinv, N, E);

  // ---- 3 GCN layers ----
  k_matmul<true, false><<<cdiv(N, 256), 256, 0, stream>>>(nullptr, tok, emb, W0, nullptr, dinv, xh, N);
  k_aggregate<<<cdiv((long)N * 64, 256), 256, 0, stream>>>(off, csrc, dinv, xh, bufA, N);

  k_matmul<false, true><<<cdiv(N, 256), 256, 0, stream>>>(bufA, nullptr, nullptr, W1, b0, dinv, xh, N);
  k_aggregate<<<cdiv((long)N * 64, 256), 256, 0, stream>>>(off, csrc, dinv, xh, bufB, N);

  k_matmul<false, true><<<cdiv(N, 256), 256, 0, stream>>>(bufB, nullptr, nullptr, W2, b1, dinv, xh, N);
  k_aggregate<<<cdiv((long)N * 64, 256), 256, 0, stream>>>(off, csrc, dinv, xh, bufA, N);

  // ---- pooling (relu+b2 fused) ----
  k_zero<<<cdiv((long)G * 129, 256), 256, 0, stream>>>(hsum, (long)G * 129);
  k_pool<<<cdiv(N, 256), 256, 0, stream>>>(bufA, b2, batch, hsum, hmax, cntg, N);

  // ---- classifier head ----
  k_cls<<<G, 64, 0, stream>>>(hsum, hmax, cntg, Wc1, bc1, Wc2, bc2, (float*)d_out);
}

// Round 6
// 449.823 us; speedup vs baseline: 2.0734x; 1.1466x over previous
//
#include <hip/hip_runtime.h>
#include <hip/hip_fp16.h>
#include <math.h>

// ---------------------------------------------------------------------------
// DevignLite: 3-layer GCN + mean/max pool + MLP head.  N=100000, E=1.6M,
// D=64, G=256.
// Round 6: aggregate rewritten for fat gathers: lane=(edge-sub g, 16B offset
// o); one dwordx4 load fetches 8 edges' 128B fp16 rows (1KB/instr), no shfl
// in the inner loop, xor-shuffle tree in epilogue.  Edge lists sub-sorted by
// src>>15 chunk (4 slabs of <=3.2MB) in k_bplace so concurrently-running
// waves gather from the same L2-resident slab (phase locality).
// Round-5 profile: aggregate latency-bound (2.47 TB/s = 39% achievable BW,
// VALUBusy 25%) + L2 capacity misses (hit 32% == 4MB/12.8MB model).
// ---------------------------------------------------------------------------

#define BKT_LOG 9
#define BKT (1 << BKT_LOG)   // 512 nodes per coarse bucket
#define CHUNK 2048           // edges per k_part block (8 per thread)
#define SRC_SHIFT 15         // src-chunk granularity: 32768 nodes = 3.2MB fp16

__global__ void k_zero(float* p, long n) {
  long i = (long)blockIdx.x * blockDim.x + threadIdx.x;
  if (i < n) p[i] = 0.0f;
}

// coarse histogram of dst >> BKT_LOG
__global__ __launch_bounds__(256) void k_chist(const int* __restrict__ dst,
                                               int* __restrict__ chist, int E, int B) {
  __shared__ int h[256];
  h[threadIdx.x] = 0;
  __syncthreads();
  for (long e = (long)blockIdx.x * blockDim.x + threadIdx.x; e < E;
       e += (long)gridDim.x * blockDim.x)
    atomicAdd(&h[dst[e] >> BKT_LOG], 1);
  __syncthreads();
  if (threadIdx.x < B && h[threadIdx.x]) atomicAdd(&chist[threadIdx.x], h[threadIdx.x]);
}

// exclusive scan of chist[B] -> cbase[B+1]; cursor copy -> gcur
__global__ __launch_bounds__(256) void k_cscan(const int* __restrict__ chist,
                                               int* __restrict__ cbase,
                                               int* __restrict__ gcur, int E, int B) {
  __shared__ int s[256];
  int v = (threadIdx.x < B) ? chist[threadIdx.x] : 0;
  s[threadIdx.x] = v;
  __syncthreads();
  for (int d = 1; d < 256; d <<= 1) {
    int t = (threadIdx.x >= (unsigned)d) ? s[threadIdx.x - d] : 0;
    __syncthreads();
    s[threadIdx.x] += t;
    __syncthreads();
  }
  if (threadIdx.x < B) {
    int ex = s[threadIdx.x] - v;
    cbase[threadIdx.x] = ex;
    gcur[threadIdx.x] = ex;
  }
  if (threadIdx.x == B) cbase[B] = E;
}

// partition pass: scatter (src,dst) pairs into coarse-bucket order.
// Block-exclusive contiguous slices -> single writer per cache line.
__global__ __launch_bounds__(256) void k_part(const int* __restrict__ src,
                                              const int* __restrict__ dst,
                                              int* __restrict__ gcur,
                                              int2* __restrict__ ebuf, int E, int B) {
  __shared__ int h[256], base[256], cur[256];
  long c0 = (long)blockIdx.x * CHUNK;
  int m = (int)min((long)CHUNK, (long)E - c0);
  int sreg[8], dreg[8];
  h[threadIdx.x] = 0;
  __syncthreads();
#pragma unroll
  for (int j = 0; j < 8; j++) {
    int idx = threadIdx.x + j * 256;
    if (idx < m) {
      sreg[j] = src[c0 + idx];
      dreg[j] = dst[c0 + idx];
      atomicAdd(&h[dreg[j] >> BKT_LOG], 1);
    }
  }
  __syncthreads();
  if (threadIdx.x < B && h[threadIdx.x])
    base[threadIdx.x] = atomicAdd(&gcur[threadIdx.x], h[threadIdx.x]);
  cur[threadIdx.x] = 0;
  __syncthreads();
#pragma unroll
  for (int j = 0; j < 8; j++) {
    int idx = threadIdx.x + j * 256;
    if (idx < m) {
      int k = dreg[j] >> BKT_LOG;
      int p = base[k] + atomicAdd(&cur[k], 1);
      ebuf[p] = make_int2(sreg[j], dreg[j]);
    }
  }
}

// per-bucket: (node, src-chunk) histogram + scan in LDS -> off/dinv, then
// place csrc sub-sorted by src>>SRC_SHIFT within each node's segment.
__global__ __launch_bounds__(512) void k_bplace(const int2* __restrict__ ebuf,
                                                const int* __restrict__ cbase,
                                                int* __restrict__ off,
                                                int* __restrict__ csrc,
                                                float* __restrict__ dinv,
                                                int N, int E) {
  __shared__ int h2[512 * 4];   // [node][src-chunk] hist, then cursors
  __shared__ int s[512];
  int b = blockIdx.x, tid = threadIdx.x;
  int n0 = b << BKT_LOG;
  int nn = min(BKT, N - n0);
  int e0 = cbase[b], e1 = cbase[b + 1];
  for (int i = tid; i < 2048; i += 512) h2[i] = 0;
  __syncthreads();
  for (int e = e0 + tid; e < e1; e += 512) {
    int2 p = ebuf[e];
    atomicAdd(&h2[((p.y - n0) << 2) + (p.x >> SRC_SHIFT)], 1);
  }
  __syncthreads();
  int deg = h2[tid * 4] + h2[tid * 4 + 1] + h2[tid * 4 + 2] + h2[tid * 4 + 3];
  s[tid] = deg;
  __syncthreads();
  for (int d = 1; d < 512; d <<= 1) {
    int t = (tid >= d) ? s[tid - d] : 0;
    __syncthreads();
    s[tid] += t;
    __syncthreads();
  }
  int excl = s[tid] - deg;
  if (tid < nn) {
    off[n0 + tid] = e0 + excl;
    dinv[n0 + tid] = 1.0f / sqrtf((float)(1 + deg));
  }
  // convert hist rows to running cursors (node excl + chunk prefix)
  {
    int run = excl;
#pragma unroll
    for (int c = 0; c < 4; c++) {
      int v = h2[tid * 4 + c];
      h2[tid * 4 + c] = run;
      run += v;
    }
  }
  __syncthreads();
  for (int e = e0 + tid; e < e1; e += 512) {
    int2 p = ebuf[e];
    int pos = e0 + atomicAdd(&h2[((p.y - n0) << 2) + (p.x >> SRC_SHIFT)], 1);
    csrc[pos] = p.x;
  }
  if (b == 0 && tid == 0) off[N] = E;
}

// ---------------------------------------------------------------------------
// Matmul, lane = row.  xw_h[row] = act(xin[row]) @ W * (256*dinv[row]), fp16.
// W read with wave-uniform loads; 64 fp32 accumulators per lane.
// ---------------------------------------------------------------------------
template <bool EMB, bool ACT>
__global__ __launch_bounds__(256) void k_matmul(const float* __restrict__ xin,
                                                const int* __restrict__ tok,
                                                const float* __restrict__ emb,
                                                const float* __restrict__ W,
                                                const float* __restrict__ bprev,
                                                const float* __restrict__ dinv,
                                                __half2* __restrict__ xwh, int n) {
  long row = (long)blockIdx.x * 256 + threadIdx.x;
  if (row >= n) return;
  const float4* W4 = (const float4*)W;
  const float4* b4 = (const float4*)bprev;
  const float4* xr;
  if (EMB) xr = (const float4*)(emb + (size_t)tok[row] * 64);
  else     xr = (const float4*)(xin + (size_t)row * 64);
  float acc[64];
#pragma unroll
  for (int i = 0; i < 64; i++) acc[i] = 0.f;

  for (int d4 = 0; d4 < 16; d4++) {
    float4 xv = xr[d4];
    if (ACT) {
      float4 bb = b4[d4];
      xv.x = fmaxf(xv.x + bb.x, 0.f);
      xv.y = fmaxf(xv.y + bb.y, 0.f);
      xv.z = fmaxf(xv.z + bb.z, 0.f);
      xv.w = fmaxf(xv.w + bb.w, 0.f);
    }
    const float xs[4] = {xv.x, xv.y, xv.z, xv.w};
#pragma unroll
    for (int r = 0; r < 4; r++) {
      const float4* wr = W4 + (size_t)(d4 * 4 + r) * 16;   // uniform address
      float x = xs[r];
#pragma unroll
      for (int cb = 0; cb < 16; cb++) {
        float4 w = wr[cb];
        acc[cb * 4 + 0] += x * w.x;
        acc[cb * 4 + 1] += x * w.y;
        acc[cb * 4 + 2] += x * w.z;
        acc[cb * 4 + 3] += x * w.w;
      }
    }
  }
  float di = dinv[row] * 256.0f;       // fp16-range scale, undone in aggregate
  __half2 hh[32];
#pragma unroll
  for (int c = 0; c < 32; c++)
    hh[c] = __float22half2_rn(make_float2(acc[2 * c] * di, acc[2 * c + 1] * di));
  uint4* dst = (uint4*)(xwh + (size_t)row * 32);
  const uint4* src = (const uint4*)hh;
#pragma unroll
  for (int k = 0; k < 8; k++) dst[k] = src[k];
}

// ---------------------------------------------------------------------------
// Aggregate: one wave per dst node.  lane = (g,o): g=edge-sub 0..7,
// o=16B-offset 0..7.  One dwordx4 gather = 8 edges' full 128B rows (1KB).
// 8 fp32 accumulators/lane; xor-shuffle reduce over g in the epilogue.
// agg[t] = (dinv[t]/256) * (xh[t] + sum_{s in in(t)} xh[s])   (fp32 out)
// ---------------------------------------------------------------------------
__global__ __launch_bounds__(256) void k_aggregate(const int* __restrict__ off,
                                                   const int* __restrict__ csrc,
                                                   const float* __restrict__ dinv,
                                                   const __half2* __restrict__ xh,
                                                   float* __restrict__ agg, int n) {
  int t = (blockIdx.x * blockDim.x + threadIdx.x) >> 6;
  if (t >= n) return;
  int lane = threadIdx.x & 63;
  int g = lane >> 3, o = lane & 7;
  const uint4* x4 = (const uint4*)xh;       // row = 8 uint4 (128 B)
  float acc[8];
#pragma unroll
  for (int k = 0; k < 8; k++) acc[k] = 0.f;

  // self term (only group 0)
  if (g == 0) {
    uint4 v = x4[(size_t)t * 8 + o];
    const __half2* hv = (const __half2*)&v;
#pragma unroll
    for (int k = 0; k < 4; k++) {
      float2 f = __half22float2(hv[k]);
      acc[2 * k] += f.x;
      acc[2 * k + 1] += f.y;
    }
  }

  int e0 = off[t], e1 = off[t + 1];
  for (int base = e0; base < e1; base += 16) {
    int i0 = base + g, i1 = base + 8 + g;
    int s0 = (i0 < e1) ? csrc[i0] : -1;
    int s1 = (i1 < e1) ? csrc[i1] : -1;
    uint4 v0, v1;
    if (s0 >= 0) v0 = x4[(size_t)s0 * 8 + o];
    if (s1 >= 0) v1 = x4[(size_t)s1 * 8 + o];
    if (s0 >= 0) {
      const __half2* hv = (const __half2*)&v0;
#pragma unroll
      for (int k = 0; k < 4; k++) {
        float2 f = __half22float2(hv[k]);
        acc[2 * k] += f.x;
        acc[2 * k + 1] += f.y;
      }
    }
    if (s1 >= 0) {
      const __half2* hv = (const __half2*)&v1;
#pragma unroll
      for (int k = 0; k < 4; k++) {
        float2 f = __half22float2(hv[k]);
        acc[2 * k] += f.x;
        acc[2 * k + 1] += f.y;
      }
    }
  }

  // reduce over edge-sub groups (lane bits 3,4,5)
#pragma unroll
  for (int m = 8; m < 64; m <<= 1) {
#pragma unroll
    for (int k = 0; k < 8; k++) acc[k] += __shfl_xor(acc[k], m);
  }

  if (g == 0) {
    float sc = dinv[t] * (1.0f / 256.0f);
    float4* p = (float4*)(agg + (size_t)t * 64 + o * 8);
    p[0] = make_float4(acc[0] * sc, acc[1] * sc, acc[2] * sc, acc[3] * sc);
    p[1] = make_float4(acc[4] * sc, acc[5] * sc, acc[6] * sc, acc[7] * sc);
  }
}

// batch is sorted: per-wave register segment reduction, flush on boundary.
__global__ __launch_bounds__(256) void k_pool(const float* __restrict__ x,
                                              const float* __restrict__ b,
                                              const int* __restrict__ batch,
                                              float* __restrict__ hsum,
                                              float* __restrict__ hmax,
                                              int* __restrict__ cntg, int n) {
  int wid = (blockIdx.x * blockDim.x + threadIdx.x) >> 6;
  int lane = threadIdx.x & 63;
  int i0 = wid * 64;
  if (i0 >= n) return;
  int i1 = min(i0 + 64, n);
  float bb = b[lane];
  int batch_l = (i0 + lane < n) ? batch[i0 + lane] : 0;
  float gsum = 0.f, gmax = 0.f;
  int cur = __shfl(batch_l, 0);
  int c = 0;
  for (int i = i0; i < i1; i++) {
    int g = __shfl(batch_l, i - i0);
    if (g != cur) {
      atomicAdd(&hsum[cur * 64 + lane], gsum);
      atomicMax((int*)&hmax[cur * 64 + lane], __float_as_int(gmax));
      if (lane == 0) atomicAdd(&cntg[cur], c);
      gsum = 0.f; gmax = 0.f; c = 0; cur = g;
    }
    float v = fmaxf(x[(long)i * 64 + lane] + bb, 0.0f);
    gsum += v;
    gmax = fmaxf(gmax, v);
    c++;
  }
  atomicAdd(&hsum[cur * 64 + lane], gsum);
  atomicMax((int*)&hmax[cur * 64 + lane], __float_as_int(gmax));
  if (lane == 0) atomicAdd(&cntg[cur], c);
}

// one block (64 threads) per graph: logits = relu(h@Wc1+bc1)@Wc2+bc2
__global__ __launch_bounds__(64) void k_cls(const float* __restrict__ hsum,
                                            const float* __restrict__ hmax,
                                            const int* __restrict__ cnt,
                                            const float* __restrict__ Wc1,
                                            const float* __restrict__ bc1,
                                            const float* __restrict__ Wc2,
                                            const float* __restrict__ bc2,
                                            float* __restrict__ out) {
  __shared__ float h[128];
  __shared__ float hid[64];
  int g = blockIdx.x, j = threadIdx.x;
  int c = cnt[g];
  float cf = (float)(c > 0 ? c : 1);
  h[j] = hsum[g * 64 + j] / cf;
  h[64 + j] = hmax[g * 64 + j];
  __syncthreads();
  float acc = bc1[j];
  for (int k = 0; k < 128; k++) acc += h[k] * Wc1[k * 64 + j];
  hid[j] = fmaxf(acc, 0.f);
  __syncthreads();
  if (j < 2) {
    float a = bc2[j];
    for (int k = 0; k < 64; k++) a += hid[k] * Wc2[k * 2 + j];
    out[g * 2 + j] = a;
  }
}

extern "C" void kernel_launch(void* const* d_in, const int* in_sizes, int n_in,
                              void* d_out, int out_size, void* d_ws, size_t ws_size,
                              hipStream_t stream) {
  const int N = in_sizes[0];
  const int E = in_sizes[1] / 2;
  const int G = out_size / 2;
  const int B = (N + BKT - 1) >> BKT_LOG;

  const int* tok   = (const int*)d_in[0];
  const int* ei    = (const int*)d_in[1];
  const int* batch = (const int*)d_in[2];
  const float* emb = (const float*)d_in[3];
  const float* W0 = (const float*)d_in[4];  const float* b0 = (const float*)d_in[5];
  const float* W1 = (const float*)d_in[6];  const float* b1 = (const float*)d_in[7];
  const float* W2 = (const float*)d_in[8];  const float* b2 = (const float*)d_in[9];
  const float* Wc1 = (const float*)d_in[10]; const float* bc1 = (const float*)d_in[11];
  const float* Wc2 = (const float*)d_in[12]; const float* bc2 = (const float*)d_in[13];
  const int* srcp = ei;
  const int* dstp = ei + E;

  // ---- workspace carve-up (4-byte units) ----
  int* off    = (int*)d_ws;                      // N+2
  int* csrc   = off + N + 2;                     // E
  float* dinv = (float*)(csrc + E);              // N
  int* chist  = (int*)(dinv + N);                // 256
  int* cbase  = chist + 256;                     // 256 (B+1 used)
  int* gcur   = cbase + 256;                     // 256
  __half2* xh = (__half2*)(gcur + 256);          // N*32 half2 (12.8 MB)
  float* bufA = (float*)((int*)(gcur + 256) + (size_t)N * 32);  // N*64 fp32
  float* bufB = bufA + (size_t)N * 64;           // N*64 fp32
  int2* ebuf  = (int2*)bufA;                     // E pairs (dead before agg0)
  float* hsum = bufB + (size_t)N * 64;           // G*64
  float* hmax = hsum + (size_t)G * 64;           // G*64
  int*   cntg = (int*)(hmax + (size_t)G * 64);   // G

  auto cdiv = [](long a, long b) { return (int)((a + b - 1) / b); };

  // ---- CSR build (single-writer placement, src-chunk sub-sorted) ----
  k_zero<<<1, 256, 0, stream>>>((float*)chist, 256);
  k_chist<<<cdiv(E, CHUNK), 256, 0, stream>>>(dstp, chist, E, B);
  k_cscan<<<1, 256, 0, stream>>>(chist, cbase, gcur, E, B);
  k_part<<<cdiv(E, CHUNK), 256, 0, stream>>>(srcp, dstp, gcur, ebuf, E, B);
  k_bplace<<<B, 512, 0, stream>>>(ebuf, cbase, off, csrc, dinv, N, E);

  // ---- 3 GCN layers ----
  k_matmul<true, false><<<cdiv(N, 256), 256, 0, stream>>>(nullptr, tok, emb, W0, nullptr, dinv, xh, N);
  k_aggregate<<<cdiv((long)N * 64, 256), 256, 0, stream>>>(off, csrc, dinv, xh, bufA, N);

  k_matmul<false, true><<<cdiv(N, 256), 256, 0, stream>>>(bufA, nullptr, nullptr, W1, b0, dinv, xh, N);
  k_aggregate<<<cdiv((long)N * 64, 256), 256, 0, stream>>>(off, csrc, dinv, xh, bufB, N);

  k_matmul<false, true><<<cdiv(N, 256), 256, 0, stream>>>(bufB, nullptr, nullptr, W2, b1, dinv, xh, N);
  k_aggregate<<<cdiv((long)N * 64, 256), 256, 0, stream>>>(off, csrc, dinv, xh, bufA, N);

  // ---- pooling (relu+b2 fused) ----
  k_zero<<<cdiv((long)G * 129, 256), 256, 0, stream>>>(hsum, (long)G * 129);
  k_pool<<<cdiv(N, 256), 256, 0, stream>>>(bufA, b2, batch, hsum, hmax, cntg, N);

  // ---- classifier head ----
  k_cls<<<G, 64, 0, stream>>>(hsum, hmax, cntg, Wc1, bc1, Wc2, bc2, (float*)d_out);
}